// Round 4
// baseline (265.798 us; speedup 1.0000x reference)
//
#include <hip/hip_runtime.h>
#include <math.h>

// Problem constants (fixed by setup_inputs)
#define BB 64
#define CC 512
#define CR 32
#define HW 3136
#define HW4 784                    // HW/4 float4 per plane
#define GROUP_B 16                 // batches per L3-resident group (102.8 MB)
#define NGROUP (BB / GROUP_B)      // 4
#define PLANES_G (GROUP_B * CC)    // 8192 planes per group

typedef float f32x4 __attribute__((ext_vector_type(4)));

// ---------------------------------------------------------------------------
// Fused dispatch: blocks [0, nscale) scale group `sg` (with inline FC gate);
// blocks [nscale, nscale+npool) pool group `pg`. One dispatch overlaps the
// HBM write stream (scale) with the HBM read stream (next group's pool).
// ---------------------------------------------------------------------------
__global__ __launch_bounds__(256) void se_fused(
    const float* __restrict__ x,
    const float* __restrict__ w1, const float* __restrict__ b1,
    const float* __restrict__ w2, const float* __restrict__ b2,
    float* __restrict__ s, float* __restrict__ out,
    int sg, int pg, int nscale)
{
    const int t = threadIdx.x;

    if ((int)blockIdx.x >= nscale) {
        // ---------------- pool: one plane of group pg ----------------
        const int p = pg * PLANES_G + ((int)blockIdx.x - nscale);
        const f32x4* x4 = reinterpret_cast<const f32x4*>(x) + (size_t)p * HW4;

        float acc = 0.0f;
        for (int i = t; i < HW4; i += 256) {
            f32x4 v = x4[i];                       // normal load -> L3 resident
            acc += (v.x + v.y) + (v.z + v.w);
        }
        #pragma unroll
        for (int off = 32; off > 0; off >>= 1)
            acc += __shfl_down(acc, off, 64);

        __shared__ float red[4];
        if ((t & 63) == 0) red[t >> 6] = acc;
        __syncthreads();
        if (t == 0) {
            float m = (red[0] + red[1]) + (red[2] + red[3]);
            s[p] = m * (1.0f / (float)HW);
        }
        return;
    }

    // ---------------- scale: one plane of group sg, inline FC ----------------
    const int p = sg * PLANES_G + (int)blockIdx.x;
    const int b = p >> 9;                          // CC == 512
    const int c = p & (CC - 1);

    __shared__ float s_sh[CC];
    __shared__ float h_sh[CR];
    __shared__ float gv_sh;

    const float* srow = s + b * CC;
    s_sh[t]       = srow[t];
    s_sh[t + 256] = srow[t + 256];
    __syncthreads();

    // h[r] = relu(b1[r] + sum_c s[c']*w1[r,c']); 8 threads per row r.
    {
        const int r = t >> 3, part = t & 7;
        const float* wr = w1 + r * CC;
        float ha = 0.0f;
        #pragma unroll
        for (int k = 0; k < CC / 8; ++k) {
            const int cc = part + 8 * k;
            ha = fmaf(s_sh[cc], wr[cc], ha);
        }
        ha += __shfl_down(ha, 4, 8);
        ha += __shfl_down(ha, 2, 8);
        ha += __shfl_down(ha, 1, 8);
        if (part == 0) h_sh[r] = fmaxf(ha + b1[r], 0.0f);
    }
    __syncthreads();

    // This block's single gate: g = sigmoid(b2[c] + h . w2[c,:])
    if (t < 32) {
        float pp = h_sh[t] * w2[c * CR + t];
        pp += __shfl_down(pp, 16, 32);
        pp += __shfl_down(pp, 8, 32);
        pp += __shfl_down(pp, 4, 32);
        pp += __shfl_down(pp, 2, 32);
        pp += __shfl_down(pp, 1, 32);
        if (t == 0) gv_sh = 1.0f / (1.0f + expf(-(pp + b2[c])));
    }
    __syncthreads();
    const float gv = gv_sh;

    const size_t base = (size_t)p * HW4;
    const f32x4* x4 = reinterpret_cast<const f32x4*>(x) + base;   // L3 hits
    f32x4*       o4 = reinterpret_cast<f32x4*>(out) + base;
    for (int i = t; i < HW4; i += 256) {
        f32x4 v = x4[i] * gv;
        __builtin_nontemporal_store(v, &o4[i]);    // don't evict next chunk
    }
}

// ---------------------------------------------------------------------------
extern "C" void kernel_launch(void* const* d_in, const int* in_sizes, int n_in,
                              void* d_out, int out_size, void* d_ws, size_t ws_size,
                              hipStream_t stream) {
    const float* x  = (const float*)d_in[0];
    const float* w1 = (const float*)d_in[1];
    const float* b1 = (const float*)d_in[2];
    const float* w2 = (const float*)d_in[3];
    const float* b2 = (const float*)d_in[4];
    float* out = (float*)d_out;

    float* s = (float*)d_ws;                       // [BB*CC] = 128 KB

    // d1: pool(0)
    se_fused<<<PLANES_G, 256, 0, stream>>>(x, w1, b1, w2, b2, s, out,
                                           /*sg=*/0, /*pg=*/0, /*nscale=*/0);
    // d2..d4: scale(g) + pool(g+1)
    for (int g2 = 0; g2 < NGROUP - 1; ++g2)
        se_fused<<<2 * PLANES_G, 256, 0, stream>>>(x, w1, b1, w2, b2, s, out,
                                                   g2, g2 + 1, PLANES_G);
    // d5: scale(NGROUP-1)
    se_fused<<<PLANES_G, 256, 0, stream>>>(x, w1, b1, w2, b2, s, out,
                                           NGROUP - 1, 0, PLANES_G);
}

// Round 5
// 217.127 us; speedup vs baseline: 1.2242x; 1.2242x over previous
//
#include <hip/hip_runtime.h>
#include <math.h>

// Problem constants (fixed by setup_inputs)
#define BB 64
#define CC 512
#define CR 32
#define HW 3136
#define HW4 784                    // HW/4 float4 per plane
#define GROUP_B 32                 // batches per L3-resident group (205.6 MB < 256 MB L3)
#define NGROUP (BB / GROUP_B)      // 2
#define PLANES_G (GROUP_B * CC)    // 16384 planes per group
#define WPB 4                      // waves per block (256 threads)

typedef float f32x4 __attribute__((ext_vector_type(4)));

// ---------------------------------------------------------------------------
// Kernel 1: global average pool. One WAVE per (b,c) plane — no LDS, no
// __syncthreads; reduce is 6 shfls. Normal loads so x lands in L3.
// ---------------------------------------------------------------------------
__global__ __launch_bounds__(256) void se_pool(const float* __restrict__ x,
                                               float* __restrict__ s, int group) {
    const int wave = threadIdx.x >> 6;
    const int lane = threadIdx.x & 63;
    const int p = group * PLANES_G + blockIdx.x * WPB + wave;
    const f32x4* x4 = reinterpret_cast<const f32x4*>(x) + (size_t)p * HW4;

    float acc = 0.0f;
    for (int i = lane; i < HW4; i += 64) {         // 13 iters (12 full + tail)
        f32x4 v = x4[i];
        acc += (v.x + v.y) + (v.z + v.w);
    }
    #pragma unroll
    for (int off = 32; off > 0; off >>= 1)
        acc += __shfl_down(acc, off, 64);
    if (lane == 0)
        s[p] = acc * (1.0f / (float)HW);
}

// ---------------------------------------------------------------------------
// Kernel 2: FC bottleneck + sigmoid gate. One block per batch of this group.
// ---------------------------------------------------------------------------
__global__ __launch_bounds__(256) void se_fc(
    const float* __restrict__ s,
    const float* __restrict__ w1, const float* __restrict__ b1,
    const float* __restrict__ w2, const float* __restrict__ b2,
    float* __restrict__ g, int group)
{
    const int b = group * GROUP_B + blockIdx.x;
    const int t = threadIdx.x;
    __shared__ float s_sh[CC];
    __shared__ float h_sh[CR];

    s_sh[t]       = s[b * CC + t];
    s_sh[t + 256] = s[b * CC + t + 256];
    __syncthreads();

    // h[r] = relu(b1[r] + sum_c s[c]*w1[r,c]); 8 threads per row r.
    const int r = t >> 3, part = t & 7;
    const float* wr = w1 + r * CC;
    float ha = 0.0f;
    #pragma unroll
    for (int k = 0; k < CC / 8; ++k) {
        const int c = part + 8 * k;
        ha = fmaf(s_sh[c], wr[c], ha);
    }
    ha += __shfl_down(ha, 4, 8);
    ha += __shfl_down(ha, 2, 8);
    ha += __shfl_down(ha, 1, 8);
    if (part == 0) h_sh[r] = fmaxf(ha + b1[r], 0.0f);
    __syncthreads();

    // g[b, c2] = sigmoid(b2[c2] + sum_r h[r]*w2[c2,r]); 2 gates per thread.
    #pragma unroll
    for (int j = 0; j < 2; ++j) {
        const int c2 = t + j * 256;
        float a2 = b2[c2];
        const float* w2r = w2 + c2 * CR;
        #pragma unroll
        for (int rr = 0; rr < CR; ++rr)
            a2 = fmaf(h_sh[rr], w2r[rr], a2);
        g[b * CC + c2] = 1.0f / (1.0f + expf(-a2));
    }
}

// ---------------------------------------------------------------------------
// Kernel 3: scale. One WAVE per plane; x chunk is L3-resident from the pool
// pass. Nontemporal stores keep `out` from evicting the chunk.
// ---------------------------------------------------------------------------
__global__ __launch_bounds__(256) void se_scale(
    const float* __restrict__ x, const float* __restrict__ g,
    float* __restrict__ out, int group)
{
    const int wave = threadIdx.x >> 6;
    const int lane = threadIdx.x & 63;
    const int p = group * PLANES_G + blockIdx.x * WPB + wave;
    const float gv = g[p];                         // same addr across wave -> broadcast
    const size_t base = (size_t)p * HW4;
    const f32x4* x4 = reinterpret_cast<const f32x4*>(x) + base;
    f32x4*       o4 = reinterpret_cast<f32x4*>(out) + base;
    for (int i = lane; i < HW4; i += 64) {
        f32x4 v = x4[i] * gv;
        __builtin_nontemporal_store(v, &o4[i]);
    }
}

// ---------------------------------------------------------------------------
extern "C" void kernel_launch(void* const* d_in, const int* in_sizes, int n_in,
                              void* d_out, int out_size, void* d_ws, size_t ws_size,
                              hipStream_t stream) {
    const float* x  = (const float*)d_in[0];
    const float* w1 = (const float*)d_in[1];
    const float* b1 = (const float*)d_in[2];
    const float* w2 = (const float*)d_in[3];
    const float* b2 = (const float*)d_in[4];
    float* out = (float*)d_out;

    float* s = (float*)d_ws;                       // [BB*CC] = 128 KB
    float* g = s + BB * CC;                        // [BB*CC] = 128 KB

    for (int grp = 0; grp < NGROUP; ++grp) {
        se_pool <<<PLANES_G / WPB, 256, 0, stream>>>(x, s, grp);
        se_fc   <<<GROUP_B, 256, 0, stream>>>(s, w1, b1, w2, b2, g, grp);
        se_scale<<<PLANES_G / WPB, 256, 0, stream>>>(x, g, out, grp);
    }
}